// Round 11
// baseline (378.545 us; speedup 1.0000x reference)
//
#include <hip/hip_runtime.h>
#include <hip/hip_bf16.h>

#define LL 512
#define HH 128
#define NBATCH 2
#define NT 32
#define NOFF (NT*(NT-1)/2)   // 496 pairs ti<tj
#define NBLK (NOFF + NT)     // 528

typedef float f32x4 __attribute__((ext_vector_type(4)));
typedef short s16x8 __attribute__((ext_vector_type(8)));
typedef unsigned int u32x4 __attribute__((ext_vector_type(4)));

__device__ __forceinline__ unsigned short f2bfu(float f){
  __hip_bfloat16 h = __float2bfloat16(f);
  return __builtin_bit_cast(unsigned short, h);
}
__device__ __forceinline__ unsigned int bmax2(unsigned int a, unsigned int b){
  float lo = fmaxf(__uint_as_float(a << 16), __uint_as_float(b << 16));
  float hi = fmaxf(__uint_as_float(a & 0xFFFF0000u), __uint_as_float(b & 0xFFFF0000u));
  return __float_as_uint(hi) | (__float_as_uint(lo) >> 16);
}
__device__ __forceinline__ unsigned int packbf2(float lo, float hi){
  return ((__float_as_uint(hi) + 0x8000u) & 0xFFFF0000u)
       | ((__float_as_uint(lo) + 0x8000u) >> 16);
}
__device__ __forceinline__ u32x4 bmax4(u32x4 a, u32x4 b){
  u32x4 r; r[0]=bmax2(a[0],b[0]); r[1]=bmax2(a[1],b[1]);
  r[2]=bmax2(a[2],b[2]); r[3]=bmax2(a[3],b[3]); return r;
}
// gelu ~ v*sigmoid(1.702 v): max err ~0.02 (budget: thr 0.152, bf16-mfma uses 0.031)
__device__ __forceinline__ float gelu_f(float v){
  float e = __expf(v * -1.702f);
  return v * __fdividef(1.0f, 1.0f + e);
}
__device__ __forceinline__ f32x4 gelu4(f32x4 v){
  f32x4 r;
  #pragma unroll
  for (int i=0;i<4;++i) r[i] = gelu_f(v[i]);
  return r;
}

// ---- prep: t1/t2 (1024 blocks), tilemax (32), Wcb bf16 (8) ----
__global__ void prep_kernel(const float* __restrict__ x, const float* __restrict__ y,
                            const float* __restrict__ W, const float* __restrict__ bias,
                            float* __restrict__ t1, float* __restrict__ t2,
                            float* __restrict__ tilemax, short* __restrict__ Wcb){
  int blk = blockIdx.x, tid = threadIdx.x;
  if (blk < NBATCH*LL){
    int b = blk >> 9, l = blk & (LL-1);
    __shared__ float xs[HH], ys[HH];
    size_t base = ((size_t)b*LL + l)*HH;
    if (tid < HH) xs[tid] = x[base + tid];
    else          ys[tid-HH] = y[base + tid - HH];
    __syncthreads();
    int role = tid >> 7, g = tid & (HH-1);
    const float4* wr = (const float4*)(W + (size_t)g*384 + role*HH);
    const float4* vs = (const float4*)(role ? ys : xs);
    float sA = 0.f, sB = 0.f;
    #pragma unroll
    for (int q=0;q<32;q+=2){
      float4 a = vs[q],   w1 = wr[q];
      sA = fmaf(a.x,w1.x, fmaf(a.y,w1.y, fmaf(a.z,w1.z, fmaf(a.w,w1.w, sA))));
      float4 c = vs[q+1], w2 = wr[q+1];
      sB = fmaf(c.x,w2.x, fmaf(c.y,w2.y, fmaf(c.z,w2.z, fmaf(c.w,w2.w, sB))));
    }
    float s = sA + sB;
    if (role == 0) t1[base + g] = s + bias[g];
    else           t2[base + g] = s;
  } else if (blk < NBATCH*LL + NBATCH*NT/2){
    int e = (blk - NBATCH*LL)*2 + (tid >> 7);
    int h = tid & (HH-1);
    int b = e >> 5, t = e & 31;
    float m = -INFINITY;
    #pragma unroll
    for (int r=0;r<16;++r) m = fmaxf(m, x[((size_t)b*LL + t*16 + r)*HH + h]);
    tilemax[(size_t)e*HH + h] = m;
  } else {
    int e0 = ((blk - (NBATCH*LL + NBATCH*NT/2))*256 + tid)*8;
    #pragma unroll
    for (int q=0;q<8;++q){
      int e = e0 + q; int g = e >> 7, h = e & (HH-1);
      Wcb[e] = (short)f2bfu(W[(size_t)g*384 + 256 + h]);
    }
  }
}

// ---- TMR[b][t0][t1][h] = max over tiles strictly between t0,t1 (bf16) ----
__global__ void tmr_kernel(const float* __restrict__ tilemax, short* __restrict__ TMR){
  int blk = blockIdx.x;            // b*NT + t0
  int b = blk >> 5, t0 = blk & 31;
  int h = threadIdx.x;             // 128 threads
  float tm[NT];
  #pragma unroll
  for (int t=0;t<NT;++t) tm[t] = tilemax[((size_t)(b*NT)+t)*HH + h];
  const size_t rb = ((size_t)(b*NT)+t0)*NT;
  float run = -INFINITY;
  for (int tb=t0+1; tb<NT; ++tb){
    TMR[(rb + tb)*HH + h] = (short)f2bfu(run);
    run = fmaxf(run, tm[tb]);
  }
  run = -INFINITY;
  for (int tb=t0-1; tb>=0; --tb){
    TMR[(rb + tb)*HH + h] = (short)f2bfu(run);
    run = fmaxf(run, tm[tb]);
  }
}

// ---- main: 256t / 4 waves, one tile-pair per block, 16 KB LDS, 6 blocks/CU ----
__global__ __launch_bounds__(256, 6) void ctx_kernel(
    const float* __restrict__ x, const float* __restrict__ t1,
    const float* __restrict__ t2, const short* __restrict__ TMR,
    const short* __restrict__ Wcb, float* __restrict__ out)
{
  __shared__ __align__(16) unsigned short shs[8192];  // 16 KB
  const int tid = threadIdx.x;
  const int b = blockIdx.y;
  // XCD-chunked swizzle (528 = 8*66, bijective): same-XCD blocks share ti
  const int bid = ((blockIdx.x & 7) * (NBLK/8)) + (blockIdx.x >> 3);
  const int w = tid >> 6, l = tid & 63, l16 = l & 15, lhi = l >> 4;
  const size_t bL = (size_t)b*LL;
  const bool isdiag = (bid >= NOFF);
  int ti, tj;
  if (!isdiag){
    int rem = bid; ti = 0;
    while (rem >= NT-1-ti){ rem -= NT-1-ti; ++ti; }
    tj = ti + 1 + rem;
  } else { ti = tj = bid - NOFF; }

  unsigned short* sIU  = shs;          // [16][128] sfx of ti tile (off-diag)
  unsigned short* pfgU = shs + 2048;   // [16][128] pfx of tj tile + gap folded
  unsigned short* M    = shs;          // diag: [4][16][128] sparse table

  if (!isdiag){
    int role = tid >> 7, h = tid & (HH-1);
    if (role == 0){
      const float* xp = x + (bL + ti*16)*HH + h;
      float run = -INFINITY;
      #pragma unroll
      for (int r=15;r>=0;--r){ run = fmaxf(run, xp[r*HH]);
        sIU[r*HH + (h ^ ((r&7)<<3))] = f2bfu(run); }
    } else {
      // gap init from TMR (one broadcast row; no serial global chain)
      unsigned short tg = (unsigned short)TMR[(((size_t)(b*NT)+ti)*NT + tj)*HH + h];
      float run = __uint_as_float(((unsigned int)tg) << 16);
      const float* xp = x + (bL + tj*16)*HH + h;
      #pragma unroll
      for (int r=0;r<16;++r){ run = fmaxf(run, xp[r*HH]);
        pfgU[r*HH + (h ^ ((r&7)<<3))] = f2bfu(run); }
    }
    __syncthreads();
  } else {
    { int e = tid*8; int r = e >> 7, h0 = e & (HH-1);
      const float* xp = x + (bL + ti*16 + r)*HH + h0;
      f32x4 v0 = *(const f32x4*)xp, v1 = *(const f32x4*)(xp+4);
      u32x4 pk; pk[0]=packbf2(v0[0],v0[1]); pk[1]=packbf2(v0[2],v0[3]);
      pk[2]=packbf2(v1[0],v1[1]); pk[3]=packbf2(v1[2],v1[3]);
      *(u32x4*)&M[r*HH + (h0 ^ ((r&7)<<3))] = pk;
    }
    __syncthreads();
    #pragma unroll
    for (int k=1;k<4;++k){
      int e = tid*8; int r = e >> 7, h0 = e & (HH-1);
      int r2 = min(r + (1<<(k-1)), 15);
      u32x4 a = *(const u32x4*)&M[((k-1)*16 + r )*HH + (h0 ^ ((r &7)<<3))];
      u32x4 c = *(const u32x4*)&M[((k-1)*16 + r2)*HH + (h0 ^ ((r2&7)<<3))];
      *(u32x4*)&M[(k*16 + r)*HH + (h0 ^ ((r&7)<<3))] = bmax4(a, c);
      __syncthreads();
    }
  }

  const int i0 = ti*16, j0 = tj*16;

  if (!isdiag){
    // hoist the j-side fragment (fixed per lane)
    u32x4 pj[4];
    #pragma unroll
    for (int kb=0;kb<4;++kb){
      int h0 = kb*32 + lhi*8;
      pj[kb] = *(const u32x4*)&pfgU[l16*HH + (h0 ^ ((l16&7)<<3))];
    }
    for (int p=0; p<4; ++p){
      const int pt = w*4 + p;
      u32x4 fr[4];
      #pragma unroll
      for (int kb=0;kb<4;++kb){
        int h0 = kb*32 + lhi*8;
        u32x4 si = *(const u32x4*)&sIU[pt*HH + (h0 ^ ((pt&7)<<3))];
        fr[kb] = bmax4(si, pj[kb]);
      }
      const size_t ioff = (bL + i0 + pt)*HH;
      const size_t joff = (bL + j0 + l16)*HH;
      #pragma unroll
      for (int nt=0; nt<8; ++nt){
        s16x8 wcf[4];
        #pragma unroll
        for (int kb=0;kb<4;++kb)
          wcf[kb] = *(const s16x8*)(Wcb + (size_t)(nt*16 + l16)*HH + kb*32 + lhi*8);
        f32x4 acc = (f32x4){0.f,0.f,0.f,0.f};
        #pragma unroll
        for (int kb=0;kb<4;++kb)
          acc = __builtin_amdgcn_mfma_f32_16x16x32_bf16(wcf[kb],
                  __builtin_bit_cast(s16x8, fr[kb]), acc, 0, 0, 0);
        const int g0 = nt*16 + lhi*4;
        f32x4 t1i = *(const f32x4*)(t1 + ioff + g0);
        f32x4 t2j = *(const f32x4*)(t2 + joff + g0);
        *(f32x4*)(out + ((bL + i0 + pt)*LL + j0 + l16)*HH + g0) = gelu4(acc + t1i + t2j);
        f32x4 t1j = *(const f32x4*)(t1 + joff + g0);
        f32x4 t2i = *(const f32x4*)(t2 + ioff + g0);
        *(f32x4*)(out + ((bL + j0 + l16)*LL + i0 + pt)*HH + g0) = gelu4(acc + t1j + t2i);
      }
    }
  } else {
    for (int p=0; p<4; ++p){
      const int pt = w*4 + p;
      int a = min(pt, l16), bb = max(pt, l16);
      int len = bb - a + 1;
      int k = 31 - __clz(len); if (k > 3) k = 3;
      int r2 = bb + 1 - (1 << k);
      u32x4 fr[4];
      #pragma unroll
      for (int kb=0;kb<4;++kb){
        int h0 = kb*32 + lhi*8;
        u32x4 ua = *(const u32x4*)&M[(k*16 + a )*HH + (h0 ^ ((a &7)<<3))];
        u32x4 ub = *(const u32x4*)&M[(k*16 + r2)*HH + (h0 ^ ((r2&7)<<3))];
        fr[kb] = bmax4(ua, ub);
      }
      const size_t ioff = (bL + i0 + pt)*HH;
      const size_t joff = (bL + j0 + l16)*HH;
      #pragma unroll
      for (int nt=0; nt<8; ++nt){
        s16x8 wcf[4];
        #pragma unroll
        for (int kb=0;kb<4;++kb)
          wcf[kb] = *(const s16x8*)(Wcb + (size_t)(nt*16 + l16)*HH + kb*32 + lhi*8);
        f32x4 acc = (f32x4){0.f,0.f,0.f,0.f};
        #pragma unroll
        for (int kb=0;kb<4;++kb)
          acc = __builtin_amdgcn_mfma_f32_16x16x32_bf16(wcf[kb],
                  __builtin_bit_cast(s16x8, fr[kb]), acc, 0, 0, 0);
        const int g0 = nt*16 + lhi*4;
        f32x4 t1i = *(const f32x4*)(t1 + ioff + g0);
        f32x4 t2j = *(const f32x4*)(t2 + joff + g0);
        *(f32x4*)(out + ((bL + i0 + pt)*LL + j0 + l16)*HH + g0) = gelu4(acc + t1i + t2j);
      }
    }
  }
}

extern "C" void kernel_launch(void* const* d_in, const int* in_sizes, int n_in,
                              void* d_out, int out_size, void* d_ws, size_t ws_size,
                              hipStream_t stream) {
  const float* x    = (const float*)d_in[0];
  const float* y    = (const float*)d_in[1];
  const float* W    = (const float*)d_in[2];
  const float* bias = (const float*)d_in[3];
  float* out = (float*)d_out;

  float* t1      = (float*)d_ws;                       // B*L*H f32
  float* t2      = t1 + (size_t)NBATCH*LL*HH;          // B*L*H f32
  float* tilemax = t2 + (size_t)NBATCH*LL*HH;          // B*NT*H f32
  short* Wcb = (short*)(tilemax + (size_t)NBATCH*NT*HH);   // 128*128 bf16
  short* TMR = Wcb + (size_t)HH*HH;                    // B*NT*NT*H bf16

  prep_kernel<<<NBATCH*LL + NBATCH*NT/2 + 8, 256, 0, stream>>>(
      x, y, W, bias, t1, t2, tilemax, Wcb);
  tmr_kernel<<<NBATCH*NT, HH, 0, stream>>>(tilemax, TMR);
  ctx_kernel<<<dim3(NBLK, NBATCH), 256, 0, stream>>>(
      x, t1, t2, TMR, Wcb, out);
}

// Round 12
// 123.498 us; speedup vs baseline: 3.0652x; 3.0652x over previous
//
#include <hip/hip_runtime.h>
#include <hip/hip_bf16.h>

#define LL 512
#define HH 128
#define NBATCH 2
#define NT 32

typedef float f32x4 __attribute__((ext_vector_type(4)));
typedef short s16x8 __attribute__((ext_vector_type(8)));
typedef unsigned int u32x4 __attribute__((ext_vector_type(4)));

__device__ __forceinline__ unsigned short f2bfu(float f){
  __hip_bfloat16 h = __float2bfloat16(f);
  return __builtin_bit_cast(unsigned short, h);
}
__device__ __forceinline__ unsigned int bmax2(unsigned int a, unsigned int b){
  float lo = fmaxf(__uint_as_float(a << 16), __uint_as_float(b << 16));
  float hi = fmaxf(__uint_as_float(a & 0xFFFF0000u), __uint_as_float(b & 0xFFFF0000u));
  return __float_as_uint(hi) | (__float_as_uint(lo) >> 16);
}
__device__ __forceinline__ u32x4 bmax4(u32x4 a, u32x4 b){
  u32x4 r; r[0]=bmax2(a[0],b[0]); r[1]=bmax2(a[1],b[1]);
  r[2]=bmax2(a[2],b[2]); r[3]=bmax2(a[3],b[3]); return r;
}
// gelu ~ v*sigmoid(1.702 v): adds <=0.02 err (budget 0.152; bf16-mfma uses 0.047)
__device__ __forceinline__ float gelu_f(float v){
  float e = __expf(v * -1.702f);
  return v * __fdividef(1.0f, 1.0f + e);
}
__device__ __forceinline__ f32x4 gelu4(f32x4 v){
  f32x4 r;
  #pragma unroll
  for (int i=0;i<4;++i) r[i] = gelu_f(v[i]);
  return r;
}

// ---- prep1: t1 f32 / t2b bf16 (1024) | pfx/sfx/tilemax/ST (64) | Wcb (8) ----
__global__ void prep_kernel(const float* __restrict__ x, const float* __restrict__ y,
                            const float* __restrict__ W, const float* __restrict__ bias,
                            float* __restrict__ t1, unsigned short* __restrict__ t2b,
                            float* __restrict__ tilemax, short* __restrict__ pfxT,
                            short* __restrict__ sfxT, short* __restrict__ ST,
                            short* __restrict__ Wcb){
  int blk = blockIdx.x, tid = threadIdx.x;
  if (blk < NBATCH*LL){
    int b = blk >> 9, ll = blk & (LL-1);
    __shared__ float xs[HH], ys[HH];
    size_t base = ((size_t)b*LL + ll)*HH;
    if (tid < HH) xs[tid] = x[base + tid];
    else          ys[tid-HH] = y[base + tid - HH];
    __syncthreads();
    int role = tid >> 7, g = tid & (HH-1);
    const float4* wr = (const float4*)(W + (size_t)g*384 + role*HH);
    const float4* vs = (const float4*)(role ? ys : xs);
    float sA = 0.f, sB = 0.f;
    #pragma unroll
    for (int q=0;q<32;q+=2){
      float4 a = vs[q],   w1 = wr[q];
      sA = fmaf(a.x,w1.x, fmaf(a.y,w1.y, fmaf(a.z,w1.z, fmaf(a.w,w1.w, sA))));
      float4 c = vs[q+1], w2 = wr[q+1];
      sB = fmaf(c.x,w2.x, fmaf(c.y,w2.y, fmaf(c.z,w2.z, fmaf(c.w,w2.w, sB))));
    }
    float s = sA + sB;
    if (role == 0) t1[base + g] = s + bias[g];
    else           t2b[base + g] = f2bfu(s);
  } else if (blk < NBATCH*LL + NBATCH*NT){
    int e = blk - NBATCH*LL;      // (b, tile)
    int b = e >> 5, t = e & 31;
    int role = tid >> 7, h = tid & (HH-1);
    const float* xp = x + ((size_t)b*LL + t*16)*HH + h;
    float v[16];
    #pragma unroll
    for (int r=0;r<16;++r) v[r] = xp[r*HH];
    const size_t rowb = ((size_t)(b*NT + t))*16;
    if (role == 0){
      float run = -INFINITY;
      #pragma unroll
      for (int r=0;r<16;++r){ run = fmaxf(run, v[r]);
        pfxT[(rowb + r)*HH + h] = (short)f2bfu(run); }
      tilemax[((size_t)(b*NT + t))*HH + h] = run;
    } else {
      float run = -INFINITY;
      #pragma unroll
      for (int r=15;r>=0;--r){ run = fmaxf(run, v[r]);
        sfxT[(rowb + r)*HH + h] = (short)f2bfu(run); }
      const size_t stb = ((size_t)(b*NT + t))*4*16;
      float cur[16];
      #pragma unroll
      for (int r=0;r<16;++r){ cur[r] = v[r];
        ST[(stb + r)*HH + h] = (short)f2bfu(v[r]); }
      #pragma unroll
      for (int k=1;k<4;++k){
        int step = 1 << (k-1);
        float nw[16];
        #pragma unroll
        for (int r=0;r<16;++r) nw[r] = fmaxf(cur[r], cur[min(r+step,15)]);
        #pragma unroll
        for (int r=0;r<16;++r){
          ST[(stb + k*16 + r)*HH + h] = (short)f2bfu(nw[r]);
          cur[r] = nw[r];
        }
      }
    }
  } else {
    int e0 = ((blk - (NBATCH*LL + NBATCH*NT))*256 + tid)*8;
    #pragma unroll
    for (int q=0;q<8;++q){
      int e = e0 + q; int g = e >> 7, h = e & (HH-1);
      Wcb[e] = (short)f2bfu(W[(size_t)g*384 + 256 + h]);
    }
  }
}

// ---- prep2: TMR[b][t0][t1][h] = max(tilemax over tiles strictly between) ----
__global__ void tmr_kernel(const float* __restrict__ tilemax, short* __restrict__ TMR){
  int blk = blockIdx.x;            // b*NT + t0
  int b = blk >> 5, t0 = blk & 31;
  int h = threadIdx.x;             // 128 threads
  float tm[NT];
  #pragma unroll
  for (int t=0;t<NT;++t) tm[t] = tilemax[((size_t)(b*NT)+t)*HH + h];
  const size_t rb = ((size_t)(b*NT)+t0)*NT;
  float run = -INFINITY;
  for (int tb=t0+1; tb<NT; ++tb){
    TMR[(rb + tb)*HH + h] = (short)f2bfu(run);
    run = fmaxf(run, tm[tb]);
  }
  run = -INFINITY;
  for (int tb=t0-1; tb>=0; --tb){
    TMR[(rb + tb)*HH + h] = (short)f2bfu(run);
    run = fmaxf(run, tm[tb]);
  }
}

// ---- main: block = (b, row i, j-half); 256t / 4 waves; wave = (g-half, j-quarter).
//      Wc frags (4nt) in registers; own-row scans in LDS; full-line stores via
//      68-word-padded wave-private LDS bounce. ----
__global__ __launch_bounds__(256, 3) void ctx_kernel(
    const float* __restrict__ t1, const unsigned short* __restrict__ t2b,
    const short* __restrict__ pfxT, const short* __restrict__ sfxT,
    const short* __restrict__ ST, const short* __restrict__ TMR,
    const short* __restrict__ Wcb, float* __restrict__ out)
{
  __shared__ __align__(16) float bounce[4][16*68];     // 17408 B
  __shared__ __align__(16) unsigned short rowS[2][HH]; // sfx / pfx of own row
  const int tid = threadIdx.x;
  const int b = blockIdx.y;
  const int i  = blockIdx.x >> 1;
  const int jh = blockIdx.x & 1;
  const int ti = i >> 4, ri = i & 15;
  const int w = tid >> 6, l = tid & 63, l16 = l & 15, lhi = l >> 4;
  const int gh = w & 1, jq = w >> 1;
  const size_t bL = (size_t)b*LL;
  const size_t bNT = (size_t)b*NT;
  float* Bw = bounce[w];

  if (tid < HH)  rowS[0][tid]    = (unsigned short)sfxT[((bNT+ti)*16 + ri)*HH + tid];
  else           rowS[1][tid-HH] = (unsigned short)pfxT[((bNT+ti)*16 + ri)*HH + (tid-HH)];
  __syncthreads();

  // register-resident Wc fragments for this wave's 4 nt (g-half gh)
  s16x8 wcf[4][4];
  #pragma unroll
  for (int n=0; n<4; ++n)
    #pragma unroll
    for (int kb=0; kb<4; ++kb)
      wcf[n][kb] = *(const s16x8*)(Wcb + (size_t)((gh*4+n)*16 + l16)*HH + kb*32 + lhi*8);

  const int gs = gh*64 + (l&15)*4;     // drain g (words)
  const f32x4 t1v = *(const f32x4*)(t1 + (bL+i)*HH + gs);
  float* orow = out + (bL + i)*LL*HH;

  #pragma unroll
  for (int tt=0; tt<8; ++tt){
    const int t = jh*16 + jq*8 + tt;

    u32x4 fr[4];
    if (t > ti){
      #pragma unroll
      for (int kb=0;kb<4;++kb){
        int h0 = kb*32 + lhi*8;
        u32x4 tm = *(const u32x4*)&TMR[((bNT+ti)*NT + t)*HH + h0];
        u32x4 sd = *(const u32x4*)&pfxT[((bNT+t)*16 + l16)*HH + h0];
        u32x4 so = *(const u32x4*)&rowS[0][h0];
        fr[kb] = bmax4(sd, bmax4(so, tm));
      }
    } else if (t < ti){
      #pragma unroll
      for (int kb=0;kb<4;++kb){
        int h0 = kb*32 + lhi*8;
        u32x4 tm = *(const u32x4*)&TMR[((bNT+ti)*NT + t)*HH + h0];
        u32x4 sd = *(const u32x4*)&sfxT[((bNT+t)*16 + l16)*HH + h0];
        u32x4 so = *(const u32x4*)&rowS[1][h0];
        fr[kb] = bmax4(sd, bmax4(so, tm));
      }
    } else {
      int a = min(ri, l16), bb = max(ri, l16);
      int len = bb - a + 1;
      int k = 31 - __clz(len); if (k > 3) k = 3;
      int r2 = bb + 1 - (1 << k);
      #pragma unroll
      for (int kb=0;kb<4;++kb){
        int h0 = kb*32 + lhi*8;
        u32x4 ua = *(const u32x4*)&ST[(((bNT+ti)*4 + k)*16 + a )*HH + h0];
        u32x4 ub = *(const u32x4*)&ST[(((bNT+ti)*4 + k)*16 + r2)*HH + h0];
        fr[kb] = bmax4(ua, ub);
      }
    }

    // t2 prefetch (bf16) for the drain
    uint2 t2p[4];
    #pragma unroll
    for (int m=0;m<4;++m){
      const int j = m*4 + (l >> 4);
      t2p[m] = *(const uint2*)(t2b + (bL + t*16 + j)*HH + gs);
    }

    // 16 MFMA, park in wave-private LDS (68-word rows: bank-rotating, no XOR)
    #pragma unroll
    for (int n=0; n<4; ++n){
      f32x4 acc = (f32x4){0.f,0.f,0.f,0.f};
      #pragma unroll
      for (int kb=0;kb<4;++kb)
        acc = __builtin_amdgcn_mfma_f32_16x16x32_bf16(wcf[n][kb],
                __builtin_bit_cast(s16x8, fr[kb]), acc, 0, 0, 0);
      *(f32x4*)&Bw[l16*68 + n*16 + lhi*4] = acc;
    }
    asm volatile("" ::: "memory");

    // drain: 4 x 1 KB stores, each = 4 rows x 256 B (full 128 B lines)
    #pragma unroll
    for (int m=0; m<4; ++m){
      const int j = m*4 + (l >> 4);
      f32x4 v = *(const f32x4*)&Bw[j*68 + (l&15)*4];
      f32x4 t2v;
      t2v[0] = __uint_as_float(t2p[m].x << 16);
      t2v[1] = __uint_as_float(t2p[m].x & 0xFFFF0000u);
      t2v[2] = __uint_as_float(t2p[m].y << 16);
      t2v[3] = __uint_as_float(t2p[m].y & 0xFFFF0000u);
      f32x4 o = gelu4(v + t1v + t2v);
      *(f32x4*)(orow + (size_t)(t*16 + j)*HH + gs) = o;
    }
    asm volatile("" ::: "memory");
  }
}

extern "C" void kernel_launch(void* const* d_in, const int* in_sizes, int n_in,
                              void* d_out, int out_size, void* d_ws, size_t ws_size,
                              hipStream_t stream) {
  const float* x    = (const float*)d_in[0];
  const float* y    = (const float*)d_in[1];
  const float* W    = (const float*)d_in[2];
  const float* bias = (const float*)d_in[3];
  float* out = (float*)d_out;

  float* t1      = (float*)d_ws;                            // B*L*H f32
  unsigned short* t2b = (unsigned short*)(t1 + (size_t)NBATCH*LL*HH); // B*L*H bf16
  float* tilemax = (float*)(t2b + (size_t)NBATCH*LL*HH);    // B*NT*H f32
  short* Wcb  = (short*)(tilemax + (size_t)NBATCH*NT*HH);   // 128*128 bf16
  short* pfxT = Wcb  + (size_t)HH*HH;                       // B*NT*16*H
  short* sfxT = pfxT + (size_t)NBATCH*NT*16*HH;             // B*NT*16*H
  short* ST   = sfxT + (size_t)NBATCH*NT*16*HH;             // B*NT*4*16*H
  short* TMR  = ST   + (size_t)NBATCH*NT*4*16*HH;           // B*NT*NT*H

  prep_kernel<<<NBATCH*LL + NBATCH*NT + 8, 256, 0, stream>>>(
      x, y, W, bias, t1, t2b, tilemax, pfxT, sfxT, ST, Wcb);
  tmr_kernel<<<NBATCH*NT, HH, 0, stream>>>(tilemax, TMR);
  ctx_kernel<<<dim3(LL*2, NBATCH), 256, 0, stream>>>(
      t1, t2b, pfxT, sfxT, ST, TMR, Wcb, out);
}

// Round 13
// 118.835 us; speedup vs baseline: 3.1855x; 1.0392x over previous
//
#include <hip/hip_runtime.h>
#include <hip/hip_bf16.h>

#define LL 512
#define HH 128
#define NBATCH 2
#define NT 32
#define NOFF (NT*(NT-1)/2)   // 496 pairs ti<tj
#define NBLK (NOFF + NT)     // 528

typedef float f32x4 __attribute__((ext_vector_type(4)));
typedef short s16x8 __attribute__((ext_vector_type(8)));
typedef unsigned int u32x4 __attribute__((ext_vector_type(4)));

__device__ __forceinline__ unsigned short f2bfu(float f){
  __hip_bfloat16 h = __float2bfloat16(f);
  return __builtin_bit_cast(unsigned short, h);
}
__device__ __forceinline__ unsigned int bmax2(unsigned int a, unsigned int b){
  float lo = fmaxf(__uint_as_float(a << 16), __uint_as_float(b << 16));
  float hi = fmaxf(__uint_as_float(a & 0xFFFF0000u), __uint_as_float(b & 0xFFFF0000u));
  return __float_as_uint(hi) | (__float_as_uint(lo) >> 16);
}
__device__ __forceinline__ unsigned int packbf2(float lo, float hi){
  return ((__float_as_uint(hi) + 0x8000u) & 0xFFFF0000u)
       | ((__float_as_uint(lo) + 0x8000u) >> 16);
}
__device__ __forceinline__ u32x4 bmax4(u32x4 a, u32x4 b){
  u32x4 r; r[0]=bmax2(a[0],b[0]); r[1]=bmax2(a[1],b[1]);
  r[2]=bmax2(a[2],b[2]); r[3]=bmax2(a[3],b[3]); return r;
}
// gelu ~ v*sigmoid(1.702 v): adds <=0.02 err (budget 0.152; measured absmax 0.047)
__device__ __forceinline__ float gelu_f(float v){
  float e = __expf(v * -1.702f);
  return v * __fdividef(1.0f, 1.0f + e);
}
__device__ __forceinline__ f32x4 gelu4(f32x4 v){
  f32x4 r;
  #pragma unroll
  for (int i=0;i<4;++i) r[i] = gelu_f(v[i]);
  return r;
}

// ---- prep: t1/t2 (1024 blocks), tilemax (16), Wcb bf16 (8) ----
__global__ void prep_kernel(const float* __restrict__ x, const float* __restrict__ y,
                            const float* __restrict__ W, const float* __restrict__ bias,
                            float* __restrict__ t1, float* __restrict__ t2,
                            float* __restrict__ tilemax, short* __restrict__ Wcb){
  int blk = blockIdx.x, tid = threadIdx.x;
  if (blk < NBATCH*LL){
    int b = blk >> 9, l = blk & (LL-1);
    __shared__ float xs[HH], ys[HH];
    size_t base = ((size_t)b*LL + l)*HH;
    if (tid < HH) xs[tid] = x[base + tid];
    else          ys[tid-HH] = y[base + tid - HH];
    __syncthreads();
    int role = tid >> 7, g = tid & (HH-1);
    const float4* wr = (const float4*)(W + (size_t)g*384 + role*HH);
    const float4* vs = (const float4*)(role ? ys : xs);
    float sA = 0.f, sB = 0.f;
    #pragma unroll
    for (int q=0;q<32;q+=2){
      float4 a = vs[q],   w1 = wr[q];
      sA = fmaf(a.x,w1.x, fmaf(a.y,w1.y, fmaf(a.z,w1.z, fmaf(a.w,w1.w, sA))));
      float4 c = vs[q+1], w2 = wr[q+1];
      sB = fmaf(c.x,w2.x, fmaf(c.y,w2.y, fmaf(c.z,w2.z, fmaf(c.w,w2.w, sB))));
    }
    float s = sA + sB;
    if (role == 0) t1[base + g] = s + bias[g];
    else           t2[base + g] = s;
  } else if (blk < NBATCH*LL + NBATCH*NT/2){
    int e = (blk - NBATCH*LL)*2 + (tid >> 7);
    int h = tid & (HH-1);
    int b = e >> 5, t = e & 31;
    float m = -INFINITY;
    #pragma unroll
    for (int r=0;r<16;++r) m = fmaxf(m, x[((size_t)b*LL + t*16 + r)*HH + h]);
    tilemax[(size_t)e*HH + h] = m;
  } else {
    int e0 = ((blk - (NBATCH*LL + NBATCH*NT/2))*256 + tid)*8;
    #pragma unroll
    for (int q=0;q<8;++q){
      int e = e0 + q; int g = e >> 7, h = e & (HH-1);
      Wcb[e] = (short)f2bfu(W[(size_t)g*384 + 256 + h]);
    }
  }
}

// ---- TMR[b][t0][t1][h] = max over tiles strictly between (bf16, symmetric) ----
__global__ void tmr_kernel(const float* __restrict__ tilemax, short* __restrict__ TMR){
  int blk = blockIdx.x;            // b*NT + t0
  int b = blk >> 5, t0 = blk & 31;
  int h = threadIdx.x;             // 128 threads
  float tm[NT];
  #pragma unroll
  for (int t=0;t<NT;++t) tm[t] = tilemax[((size_t)(b*NT)+t)*HH + h];
  const size_t rb = ((size_t)(b*NT)+t0)*NT;
  float run = -INFINITY;
  for (int tb=t0+1; tb<NT; ++tb){
    TMR[(rb + tb)*HH + h] = (short)f2bfu(run);
    run = fmaxf(run, tm[tb]);
  }
  run = -INFINITY;
  for (int tb=t0-1; tb>=0; --tb){
    TMR[(rb + tb)*HH + h] = (short)f2bfu(run);
    run = fmaxf(run, tm[tb]);
  }
}

// ---- main: pair-dedup; 256t / 4 waves = (pt-half, g-half).
//      Wc frags (4nt x 4kb = 64 VGPR) register-resident; scans in LDS;
//      drain via 68-word padded wave-private bounce; line-complete 1KB stores. ----
__global__ __launch_bounds__(256, 4) void ctx_kernel(
    const float* __restrict__ x, const float* __restrict__ t1,
    const float* __restrict__ t2, const short* __restrict__ TMR,
    const short* __restrict__ Wcb, float* __restrict__ out)
{
  __shared__ __align__(16) float bounce[4][16*68];        // 17408 B
  __shared__ __align__(16) unsigned short scanM[8192];    // 16 KB (off-diag uses 8 KB)
  const int tid = threadIdx.x;
  const int b = blockIdx.y;
  const int bid = blockIdx.x;
  const int w = tid >> 6, l = tid & 63, l16 = l & 15, lhi = l >> 4;
  const int ph = w >> 1, gh = w & 1;
  const size_t bL = (size_t)b*LL;
  const size_t bNT = (size_t)b*NT;
  float* Bw = bounce[w];

  const bool isdiag = (bid >= NOFF);
  int ti, tj;
  if (!isdiag){
    int rem = bid; ti = 0;
    while (rem >= NT-1-ti){ rem -= NT-1-ti; ++ti; }
    tj = ti + 1 + rem;
  } else { ti = tj = bid - NOFF; }

  unsigned short* sIU  = scanM;          // [16][128] sfx of ti tile
  unsigned short* pfgU = scanM + 2048;   // [16][128] pfx of tj tile + gap folded
  unsigned short* M    = scanM;          // diag: [4][16][128] sparse table

  if (!isdiag){
    int role = tid >> 7, h = tid & (HH-1);
    if (role == 0){
      const float* xp = x + (bL + ti*16)*HH + h;
      float run = -INFINITY;
      #pragma unroll
      for (int r=15;r>=0;--r){ run = fmaxf(run, xp[r*HH]);
        sIU[r*HH + (h ^ ((r&7)<<3))] = f2bfu(run); }
    } else {
      unsigned short tg = (unsigned short)TMR[((bNT+ti)*NT + tj)*HH + h];
      float run = __uint_as_float(((unsigned int)tg) << 16);
      const float* xp = x + (bL + tj*16)*HH + h;
      #pragma unroll
      for (int r=0;r<16;++r){ run = fmaxf(run, xp[r*HH]);
        pfgU[r*HH + (h ^ ((r&7)<<3))] = f2bfu(run); }
    }
    __syncthreads();
  } else {
    { int e = tid*8; int r = e >> 7, h0 = e & (HH-1);
      const float* xp = x + (bL + ti*16 + r)*HH + h0;
      f32x4 v0 = *(const f32x4*)xp, v1 = *(const f32x4*)(xp+4);
      u32x4 pk; pk[0]=packbf2(v0[0],v0[1]); pk[1]=packbf2(v0[2],v0[3]);
      pk[2]=packbf2(v1[0],v1[1]); pk[3]=packbf2(v1[2],v1[3]);
      *(u32x4*)&M[r*HH + (h0 ^ ((r&7)<<3))] = pk;
    }
    __syncthreads();
    #pragma unroll
    for (int k=1;k<4;++k){
      int e = tid*8; int r = e >> 7, h0 = e & (HH-1);
      int r2 = min(r + (1<<(k-1)), 15);
      u32x4 a = *(const u32x4*)&M[((k-1)*16 + r )*HH + (h0 ^ ((r &7)<<3))];
      u32x4 c = *(const u32x4*)&M[((k-1)*16 + r2)*HH + (h0 ^ ((r2&7)<<3))];
      *(u32x4*)&M[(k*16 + r)*HH + (h0 ^ ((r&7)<<3))] = bmax4(a, c);
      __syncthreads();
    }
  }

  // register-resident Wc fragments: this wave's g-half = 4 nt
  s16x8 wcf[4][4];
  #pragma unroll
  for (int n=0; n<4; ++n)
    #pragma unroll
    for (int kb=0; kb<4; ++kb)
      wcf[n][kb] = *(const s16x8*)(Wcb + (size_t)((gh*4+n)*16 + l16)*HH + kb*32 + lhi*8);

  // hoisted j-side fragment (off-diag)
  u32x4 pj[4];
  if (!isdiag){
    #pragma unroll
    for (int kb=0;kb<4;++kb){
      int h0 = kb*32 + lhi*8;
      pj[kb] = *(const u32x4*)&pfgU[l16*HH + (h0 ^ ((l16&7)<<3))];
    }
  }

  const int i0 = ti*16, j0 = tj*16;
  const int gs = gh*64 + (l&15)*4;          // drain g (words)
  const int jd = l >> 4;                    // drain j sub-index

  #pragma unroll
  for (int p=0; p<8; ++p){
    const int pt = ph*8 + p;

    u32x4 fr[4];
    if (!isdiag){
      #pragma unroll
      for (int kb=0;kb<4;++kb){
        int h0 = kb*32 + lhi*8;
        u32x4 si = *(const u32x4*)&sIU[pt*HH + (h0 ^ ((pt&7)<<3))];
        fr[kb] = bmax4(si, pj[kb]);
      }
    } else {
      int a = min(pt, l16), bb = max(pt, l16);
      int len = bb - a + 1;
      int k = 31 - __clz(len); if (k > 3) k = 3;
      int r2 = bb + 1 - (1 << k);
      #pragma unroll
      for (int kb=0;kb<4;++kb){
        int h0 = kb*32 + lhi*8;
        u32x4 ua = *(const u32x4*)&M[(k*16 + a )*HH + (h0 ^ ((a &7)<<3))];
        u32x4 ub = *(const u32x4*)&M[(k*16 + r2)*HH + (h0 ^ ((r2&7)<<3))];
        fr[kb] = bmax4(ua, ub);
      }
    }

    // 16 MFMA (4 nt x 4 kb), park in wave-private LDS
    #pragma unroll
    for (int n=0; n<4; ++n){
      f32x4 acc = (f32x4){0.f,0.f,0.f,0.f};
      #pragma unroll
      for (int kb=0;kb<4;++kb)
        acc = __builtin_amdgcn_mfma_f32_16x16x32_bf16(wcf[n][kb],
                __builtin_bit_cast(s16x8, fr[kb]), acc, 0, 0, 0);
      *(f32x4*)&Bw[l16*68 + n*16 + lhi*4] = acc;
    }
    asm volatile("" ::: "memory");

    // drain: o1 (and o2 if off-diag); all pieces >=256B contiguous (full lines)
    const int irow = i0 + pt;
    const f32x4 t1i = *(const f32x4*)(t1 + (bL+irow)*HH + gs);
    const f32x4 t2i = *(const f32x4*)(t2 + (bL+irow)*HH + gs);
    #pragma unroll
    for (int m=0; m<4; ++m){
      const int j = m*4 + jd;
      f32x4 v = *(const f32x4*)&Bw[j*68 + (l&15)*4];
      f32x4 t1j = *(const f32x4*)(t1 + (bL+j0+j)*HH + gs);
      f32x4 t2j = *(const f32x4*)(t2 + (bL+j0+j)*HH + gs);
      *(f32x4*)(out + ((bL+irow)*LL + j0+j)*HH + gs) = gelu4(v + t1i + t2j);
      if (!isdiag)
        *(f32x4*)(out + ((bL+j0+j)*LL + irow)*HH + gs) = gelu4(v + t1j + t2i);
    }
    asm volatile("" ::: "memory");
  }
}

extern "C" void kernel_launch(void* const* d_in, const int* in_sizes, int n_in,
                              void* d_out, int out_size, void* d_ws, size_t ws_size,
                              hipStream_t stream) {
  const float* x    = (const float*)d_in[0];
  const float* y    = (const float*)d_in[1];
  const float* W    = (const float*)d_in[2];
  const float* bias = (const float*)d_in[3];
  float* out = (float*)d_out;

  float* t1      = (float*)d_ws;                       // B*L*H f32
  float* t2      = t1 + (size_t)NBATCH*LL*HH;          // B*L*H f32
  float* tilemax = t2 + (size_t)NBATCH*LL*HH;          // B*NT*H f32
  short* Wcb = (short*)(tilemax + (size_t)NBATCH*NT*HH);   // 128*128 bf16
  short* TMR = Wcb + (size_t)HH*HH;                    // B*NT*NT*H bf16

  prep_kernel<<<NBATCH*LL + NBATCH*NT/2 + 8, 256, 0, stream>>>(
      x, y, W, bias, t1, t2, tilemax, Wcb);
  tmr_kernel<<<NBATCH*NT, HH, 0, stream>>>(tilemax, TMR);
  ctx_kernel<<<dim3(NBLK, NBATCH), 256, 0, stream>>>(
      x, t1, t2, TMR, Wcb, out);
}